// Round 6
// baseline (330.781 us; speedup 1.0000x reference)
//
#include <hip/hip_runtime.h>
#include <stdint.h>
#include <stddef.h>

// Problem constants
#define N_B   32
#define C_CH  256
#define H_S   56
#define W_S   56
#define HW    (H_S*W_S)        // 3136
#define NSP   (N_B*HW)         // 100352
#define KTOT  (C_CH*9)         // 2304 (bytes per row in i8)
#define HP    58               // padded spatial

// Workspace layout (bytes) — all i8
#define XPAD_BYTES ((size_t)N_B*HP*HP*C_CH)        // 27,557,888
#define WB_OFF_B   XPAD_BYTES
#define WB_BYTES   ((size_t)C_CH*KTOT)             // 589,824
#define Y_OFF_B    (WB_OFF_B + WB_BYTES)
#define STAT_OFF_B (Y_OFF_B + (size_t)C_CH*NSP*2)

typedef int    int4v  __attribute__((ext_vector_type(4)));
typedef int    i32x16 __attribute__((ext_vector_type(16)));
typedef short  s16x4  __attribute__((ext_vector_type(4)));
typedef char   char8  __attribute__((ext_vector_type(8)));
typedef float  f32x4v __attribute__((ext_vector_type(4)));

__device__ __forceinline__ void gl16(const void* g, void* l) {
    __builtin_amdgcn_global_load_lds((const __attribute__((address_space(1))) void*)g,
                                     (__attribute__((address_space(3))) void*)l, 16, 0, 0);
}

__device__ __forceinline__ char sign_i8(float v) {
    return v > 0.f ? (char)1 : (v < 0.f ? (char)-1 : (char)0);
}

// --- binarize weights (i8), reorder K; also zero the stat accumulators
// (exact r0 version — the streaming config with the measured-lowest gap)
__global__ __launch_bounds__(256) void k_binw(const float* __restrict__ w,
                                              char* __restrict__ wb,
                                              float* __restrict__ gStat) {
    int g = blockIdx.x * 256 + threadIdx.x;
    if (blockIdx.x == 0 && threadIdx.x < 512) gStat[threadIdx.x] = 0.f;
    if (g >= (int)WB_BYTES) return;
    int co = g / KTOT;
    int r  = g - co * KTOT;
    int ci = r / 9;
    int koff = r - ci * 9;
    wb[co * KTOT + koff * C_CH + ci] = sign_i8(w[g]);
}

// --- binarize x into zero-padded [nb][h+1][w+1][ci] i8 via LDS transpose
// (exact r0 version)
__global__ __launch_bounds__(256) void k_binx(const float* __restrict__ x,
                                              char* __restrict__ xpad) {
    __shared__ short tile[32 * 66];   // [ci_l][hw], stride 66 kills bank conflicts
    const int t   = threadIdx.x;
    const int hw0 = blockIdx.x * 64;
    const int ci0 = blockIdx.y * 32;
    const int nb  = blockIdx.z;
    const int lhw = t & 63;
    const int cq  = t >> 6;    // 0..3
#pragma unroll
    for (int p = 0; p < 8; ++p) {
        int ci_l = cq + p * 4;
        float v = x[((size_t)(nb * C_CH + ci0 + ci_l)) * HW + hw0 + lhw];
        tile[ci_l * 66 + lhw] = (short)sign_i8(v);
    }
    __syncthreads();
    const int hwi = t >> 2;    // 0..63
    const int ch  = t & 3;     // 8 ci each
    const int hw  = hw0 + hwi;
    const int h   = hw / 56, w_ = hw - h * 56;
    char8 pk;
#pragma unroll
    for (int i = 0; i < 8; ++i) pk[i] = (char)tile[(ch * 8 + i) * 66 + hwi];
    size_t dst = ((size_t)((nb * HP + h + 1) * HP + (w_ + 1))) * C_CH + ci0 + ch * 8;
    *(char8*)(xpad + dst) = pk;   // 8B aligned contiguous
}

// --- implicit-GEMM conv (i8 MFMA): y[co][nsp]; fused channel sum/sumsq
// Round-6: BK=128 2-barrier structure (r5, best) with 32x32x32 i8 MFMA:
//   * 16 MFMAs/step (was 32), each 2x ops at the higher 32x32 rate
//     (4404 vs 3944 TOPS) — halves inner-loop issue slots.
//   * Same staging + row&7 XOR chunk swizzle (conflict-free: lanes 0..31
//     span 32 consecutive rows; each 8-row group covers all 32 banks).
//   * C/D layout 32x32: col=lane&31, row=(reg&3)+8*(reg>>2)+4*(lane>>5).
__global__ __launch_bounds__(256) void k_conv(const char* __restrict__ xpad,
                                              const char* __restrict__ wb,
                                              short* __restrict__ y16,
                                              float* __restrict__ gSum,
                                              float* __restrict__ gSqs) {
    __shared__ char lA[128 * 128];   // [co_row][k 0..127], swizzled chunks
    __shared__ char lB[128 * 128];   // [n_row][k]
    __shared__ float sSum[128], sSqs[128];

    const int t    = threadIdx.x;
    const int wave = t >> 6, lane = t & 63;
    const int l31  = lane & 31, lh = lane >> 5;
    const int wm   = wave & 1, wn = wave >> 1;
    const int n0   = blockIdx.x * 128;
    const int co0  = blockIdx.y * 128;

    if (t < 128) { sSum[t] = 0.f; sSqs[t] = 0.f; }

    // Staging: wave stages rows [wave*32, +32). gl16 j (0..3) fills LDS rows
    // wave*32 + j*8 + (lane>>3), chunk (lane&7). Source chunk pre-swizzled:
    const int swz = (lane & 7) ^ (lane >> 3);   // chunk ^ (row & 7)
    uint32_t aOff[4], bOff[4];
#pragma unroll
    for (int j = 0; j < 4; ++j) {
        int row = wave * 32 + j * 8 + (lane >> 3);
        aOff[j] = (uint32_t)(co0 + row) * KTOT + swz * 16;
        int nsp = n0 + row;
        int nb = nsp / HW; int hwr = nsp - nb * HW;
        int h = hwr / 56;  int w_  = hwr - h * 56;
        bOff[j] = (uint32_t)((nb * HP + h) * HP + w_) * C_CH + swz * 16;
    }

    i32x16 acc[2][2];
#pragma unroll
    for (int i = 0; i < 2; ++i)
#pragma unroll
        for (int j = 0; j < 2; ++j)
#pragma unroll
            for (int r = 0; r < 16; ++r) acc[i][j][r] = 0;

    for (int kbb = 0; kbb < 18; ++kbb) {                  // BK=128 steps
        const int koff = kbb >> 1;                        // (kh,kw) 0..8
        const int kh   = koff / 3;
        const int kw   = koff - kh * 3;
        const uint32_t bAdd = (uint32_t)(kh * HP + kw) * C_CH + (kbb & 1) * 128;
        const uint32_t aAdd = (uint32_t)kbb * 128;
        __syncthreads();
#pragma unroll
        for (int j = 0; j < 4; ++j) gl16(wb   + aOff[j] + aAdd, &lA[wave * 4096 + j * 1024]);
#pragma unroll
        for (int j = 0; j < 4; ++j) gl16(xpad + bOff[j] + bAdd, &lB[wave * 4096 + j * 1024]);
        __syncthreads();
        int4v af[2][4], bf[2][4];
#pragma unroll
        for (int kc = 0; kc < 4; ++kc) {
            // global k-chunk g = kc*2 + lh; LDS chunk = g ^ (row&7), row&7 = l31&7
            const int cs = ((kc * 2 + lh) ^ (l31 & 7)) * 16;
            af[0][kc] = *(const int4v*)&lA[(wm * 64 +      l31) * 128 + cs];
            af[1][kc] = *(const int4v*)&lA[(wm * 64 + 32 + l31) * 128 + cs];
            bf[0][kc] = *(const int4v*)&lB[(wn * 64 +      l31) * 128 + cs];
            bf[1][kc] = *(const int4v*)&lB[(wn * 64 + 32 + l31) * 128 + cs];
        }
#pragma unroll
        for (int kc = 0; kc < 4; ++kc) {
            acc[0][0] = __builtin_amdgcn_mfma_i32_32x32x32_i8(af[0][kc], bf[0][kc], acc[0][0], 0, 0, 0);
            acc[0][1] = __builtin_amdgcn_mfma_i32_32x32x32_i8(af[0][kc], bf[1][kc], acc[0][1], 0, 0, 0);
            acc[1][0] = __builtin_amdgcn_mfma_i32_32x32x32_i8(af[1][kc], bf[0][kc], acc[1][0], 0, 0, 0);
            acc[1][1] = __builtin_amdgcn_mfma_i32_32x32x32_i8(af[1][kc], bf[1][kc], acc[1][1], 0, 0, 0);
        }
    }

    // epilogue: y16 store + per-channel partial sums
    // 32x32 C/D: col = l31 (n dim), row = (r&3) + 8*(r>>2) + 4*lh (m dim)
#pragma unroll
    for (int mi = 0; mi < 2; ++mi) {
#pragma unroll
        for (int r = 0; r < 16; ++r) {
            int m = co0 + wm * 64 + mi * 32 + (r & 3) + 8 * (r >> 2) + 4 * lh;
            float s = 0.f, sq = 0.f;
#pragma unroll
            for (int ni = 0; ni < 2; ++ni) {
                int yi = acc[mi][ni][r];      // exact integer
                float f = (float)yi;
                int n = n0 + wn * 64 + ni * 32 + l31;
                y16[(uint32_t)m * NSP + n] = (short)yi;
                s += f; sq += f * f;
            }
            // reduce over the 32 lanes sharing this m (offsets stay in-half)
#pragma unroll
            for (int off = 1; off < 32; off <<= 1) {
                s  += __shfl_xor(s, off);
                sq += __shfl_xor(sq, off);
            }
            if (l31 == 0) {
                atomicAdd(&sSum[m - co0], s);
                atomicAdd(&sSqs[m - co0], sq);
            }
        }
    }
    __syncthreads();
    if (t < 128) {
        atomicAdd(&gSum[co0 + t], sSum[t]);
        atomicAdd(&gSqs[co0 + t], sSqs[t]);
    }
}

// --- fused BN stats + apply + residual (exact r0 version)
__global__ __launch_bounds__(256) void k_out(const short* __restrict__ y16,
                                             const float* __restrict__ x,
                                             const float* __restrict__ gSum,
                                             const float* __restrict__ gSqs,
                                             const float* __restrict__ gamma,
                                             const float* __restrict__ beta,
                                             float* __restrict__ out) {
    int g = blockIdx.x * 256 + threadIdx.x;       // NSP*C_CH/4 threads
    int hw4 = g % 784;
    int tmp = g / 784;
    int co  = tmp & 255;
    int nb  = tmp >> 8;
    const float inv = 1.0f / (float)NSP;
    float mean = gSum[co] * inv;
    float var  = gSqs[co] * inv - mean * mean;
    float a = gamma[co] * rsqrtf(var + 1e-5f);
    float b = beta[co] - mean * a;
    s16x4 yv = *(const s16x4*)&y16[(uint32_t)co * NSP + nb * HW + hw4 * 4];
    size_t xi = ((size_t)(nb * C_CH + co)) * HW + hw4 * 4;
    f32x4v xv = *(const f32x4v*)&x[xi];
    f32x4v o;
#pragma unroll
    for (int i = 0; i < 4; ++i) o[i] = a * (float)yv[i] + b + xv[i];
    *(f32x4v*)&out[xi] = o;
}

extern "C" void kernel_launch(void* const* d_in, const int* in_sizes, int n_in,
                              void* d_out, int out_size, void* d_ws, size_t ws_size,
                              hipStream_t stream) {
    const float* x     = (const float*)d_in[0];
    const float* w     = (const float*)d_in[1];
    const float* gamma = (const float*)d_in[2];
    const float* beta  = (const float*)d_in[3];
    float* out = (float*)d_out;
    char* ws = (char*)d_ws;

    char*  xpad = ws;
    char*  wbp  = ws + WB_OFF_B;
    short* y16  = (short*)(ws + Y_OFF_B);
    float* gSum = (float*)(ws + STAT_OFF_B);
    float* gSqs = gSum + 256;

    hipMemsetAsync(xpad, 0, XPAD_BYTES, stream);                 // padding zeros

    k_binw<<<(int)((WB_BYTES + 255) / 256), 256, 0, stream>>>(w, wbp, gSum);
    k_binx<<<dim3(49, 8, 32), 256, 0, stream>>>(x, xpad);
    k_conv<<<dim3(NSP / 128, 2), 256, 0, stream>>>(xpad, wbp, y16, gSum, gSqs);
    k_out<<<(NSP * C_CH / 4) / 256, 256, 0, stream>>>(y16, x, gSum, gSqs, gamma, beta, out);
}